// Round 8
// baseline (119.021 us; speedup 1.0000x reference)
//
#include <hip/hip_runtime.h>

#define BB 2
#define CC 64
#define HH 128
#define WW 128
#define NN (HH*WW)          // 16384 queries per batch
#define MM ((HH/2)*(WW/2))  // 4096 keys per batch
#define CV 32
#define LOG2E 1.44269504088896f

typedef __attribute__((ext_vector_type(8))) short bf16x8;
typedef __attribute__((ext_vector_type(4))) float f32x4;
typedef unsigned int uint32;

union U8 { bf16x8 v; uint32 u[4]; };

__device__ __forceinline__ short f2bf(float f) {
    union { float f; unsigned u; } v; v.f = f;
    unsigned u = v.u + 0x7fffu + ((v.u >> 16) & 1u);   // RNE
    return (short)(u >> 16);
}
__device__ __forceinline__ uint32 pack2bf(float lo, float hi) {
    return (uint32)(unsigned short)f2bf(lo) | ((uint32)(unsigned short)f2bf(hi) << 16);
}
// 1-instr truncation pack via v_perm_b32; downward bias cancels in P/l ratio
__device__ __forceinline__ uint32 packperm(float lo, float hi) {
    union { float f; uint32 u; } a, b; a.f = lo; b.f = hi;
    return __builtin_amdgcn_perm(b.u, a.u, 0x07060302u);
}

// ---------------------------------------------------------------------------
// Kernel 1 (unchanged from R6/R7): conv1x1 + 2x2 maxpool, 4-way channel
// split. R8 DIAGNOSTIC: launched TWICE (idempotent) so that
// dur_total - 104.97us == dur(proj) exactly — the harness's 42us fill
// dispatches blind the top-5 table, and three rounds of model-based
// guessing at the proj/attn split have failed. This round buys the number.
// ---------------------------------------------------------------------------
__global__ __launch_bounds__(256, 4) void proj_kernel(
    const float* __restrict__ x, const float* __restrict__ wt,
    const float* __restrict__ wp, const float* __restrict__ wg,
    short* __restrict__ Qb, short* __restrict__ Kb, short* __restrict__ Vt)
{
    __shared__ float plds[8192];
    __shared__ float phi_lds[512];
    int tid = threadIdx.x;
    int px = tid & 63, part = tid >> 6;
    int sb = blockIdx.x >> 2, cq = blockIdx.x & 3;
    int b = blockIdx.y, z = blockIdx.z;
    int row = px >> 5, col = cq*32 + (px & 31);
    int n = (2*sb + row)*WW + col;

    float xv[16];
    #pragma unroll
    for (int i = 0; i < 16; ++i)
        xv[i] = x[((b*CC + part*16 + i) << 14) + n];

    if (z == 0) {
        float po[16];
        #pragma unroll
        for (int o = 0; o < 8; ++o) {
            float a = 0.f;
            #pragma unroll
            for (int i = 0; i < 16; ++i) a += wt[o*64 + part*16 + i]*xv[i];
            po[o] = a;
        }
        #pragma unroll
        for (int o = 0; o < 8; ++o) {
            float a = 0.f;
            #pragma unroll
            for (int i = 0; i < 16; ++i) a += wp[o*64 + part*16 + i]*xv[i];
            po[8+o] = a;
        }
        #pragma unroll
        for (int o = 0; o < 16; ++o) plds[(o*4 + part)*64 + px] = po[o];
        __syncthreads();
        int og = tid >> 6;
        float sm[4];
        #pragma unroll
        for (int j = 0; j < 4; ++j) {
            int o = og*4 + j;
            sm[j] = (plds[(o*4+0)*64+px] + plds[(o*4+1)*64+px])
                  + (plds[(o*4+2)*64+px] + plds[(o*4+3)*64+px]);
        }
        if (og < 2) {
            uint2 val;
            val.x = pack2bf(sm[0]*LOG2E, sm[1]*LOG2E);
            val.y = pack2bf(sm[2]*LOG2E, sm[3]*LOG2E);
            ((uint2*)Qb)[(b*NN + n)*2 + og] = val;
        } else {
            #pragma unroll
            for (int j = 0; j < 4; ++j)
                phi_lds[((og-2)*4 + j)*64 + px] = sm[j];
        }
        __syncthreads();
        if (tid < 128) {
            int mm = tid & 15, ch = tid >> 4;
            int p00 = 2*mm, p01 = p00+1, p10 = 32+2*mm, p11 = p10+1;
            float mx = fmaxf(fmaxf(phi_lds[ch*64+p00], phi_lds[ch*64+p01]),
                             fmaxf(phi_lds[ch*64+p10], phi_lds[ch*64+p11]));
            int m = sb*64 + cq*16 + mm;
            Kb[(b*MM + m)*8 + ch] = f2bf(mx);
        }
    } else {
        float po[32];
        #pragma unroll
        for (int o = 0; o < 32; ++o) {
            float a = 0.f;
            #pragma unroll
            for (int i = 0; i < 16; ++i) a += wg[o*64 + part*16 + i]*xv[i];
            po[o] = a;
        }
        #pragma unroll
        for (int o = 0; o < 32; ++o) plds[(o*4 + part)*64 + px] = po[o];
        __syncthreads();
        int og = tid >> 6;
        float sm[8];
        #pragma unroll
        for (int j = 0; j < 8; ++j) {
            int o = og*8 + j;
            sm[j] = (plds[(o*4+0)*64+px] + plds[(o*4+1)*64+px])
                  + (plds[(o*4+2)*64+px] + plds[(o*4+3)*64+px]);
        }
        __syncthreads();
        #pragma unroll
        for (int j = 0; j < 8; ++j)
            plds[(og*8 + j)*64 + px] = sm[j];
        __syncthreads();
        int mm = tid & 15, chb = tid >> 4;
        int p00 = 2*mm, p01 = p00+1, p10 = 32+2*mm, p11 = p10+1;
        int w64 = cq*16 + mm;
        int hh = w64 >> 5, w = w64 & 31;
        int slot = ((w >> 2) & 3)*8 + (w & 3) + ((w >> 4) << 2);
        int pos64 = hh*32 + slot;
        #pragma unroll
        for (int j = 0; j < 2; ++j) {
            int ch = chb*2 + j;
            float mx = fmaxf(fmaxf(plds[ch*64+p00], plds[ch*64+p01]),
                             fmaxf(plds[ch*64+p10], plds[ch*64+p11]));
            int colv = (pos64 >> 3) ^ (ch & 7);
            Vt[(b*CV + ch)*MM + sb*64 + colv*8 + (pos64 & 7)] = f2bf(mx);
        }
    }
}

// ---------------------------------------------------------------------------
// Kernel 2 (unchanged from R7): fused attention, 32 q/wave, 4 quarter-windows.
// ---------------------------------------------------------------------------
__global__ __launch_bounds__(512, 4) void attn_kernel(
    const short* __restrict__ Qb, const short* __restrict__ Kb,
    const short* __restrict__ Vt, const float* __restrict__ x,
    const float* __restrict__ wo, const float* __restrict__ gamma,
    float* __restrict__ out)
{
    __shared__ short ldsK[2][4][512];    // [buf][qtr][64key x 8ch]
    __shared__ short ldsV[2][4][2048];   // [buf][qtr][32ch x 64key swizzled]
    __shared__ float comb[2][2][576];    // [qpair][tile][lane*9]
    int tid = threadIdx.x;
    int wave = tid >> 6, lane = tid & 63;
    int quad = lane >> 4, c15 = lane & 15, sw = c15 & 7;
    int qtr = wave >> 1, qpair = wave & 1;
    int blk = blockIdx.x;
    int b = blk >> 8;
    int qblk = (blk & 255)*64;
    int q0 = qblk + qpair*32;            // tiles q0, q0+16

    const f32x4 zero4 = {0.f, 0.f, 0.f, 0.f};
    bf16x8 zero8 = (bf16x8)0;
    U8 ones; ones.u[0] = ones.u[1] = ones.u[2] = ones.u[3] = 0x3F803F80u;

    bf16x8 bq0 = (quad == 0) ? ((const bf16x8*)Qb)[b*NN + q0 + c15]      : zero8;
    bf16x8 bq1 = (quad == 0) ? ((const bf16x8*)Qb)[b*NN + q0 + 16 + c15] : zero8;

    // staging roles
    int sqtr = tid >> 7, sub = tid & 127;
    int sch = sub >> 2, spart = sub & 3;
    const short* Vg = Vt + ((size_t)b*CV + sch)*MM + sqtr*1024 + spart*16;
    int vofs = sch*64 + spart*16;
    int kqtr = tid >> 6, kofs = (tid & 63)*8;
    const short* Kg = Kb + (size_t)b*MM*8 + (kqtr*1024 + (tid & 63))*8;

    {   // stage 0
        uint4 v0 = *(const uint4*)(Vg);
        uint4 v1 = *(const uint4*)(Vg + 8);
        *(uint4*)&ldsV[0][sqtr][vofs]     = v0;
        *(uint4*)&ldsV[0][sqtr][vofs + 8] = v1;
        if (tid < 256) { uint4 k = *(const uint4*)Kg; *(uint4*)&ldsK[0][kqtr][kofs] = k; }
    }
    __syncthreads();

    f32x4 D0A = zero4, D1A = zero4, DlA = zero4;
    f32x4 D0B = zero4, D1B = zero4, DlB = zero4;

    for (int sc = 0; sc < 16; ++sc) {
        int scn = (sc + 1 > 15) ? 15 : sc + 1;
        uint4 nv0 = *(const uint4*)(Vg + scn*64);
        uint4 nv1 = *(const uint4*)(Vg + scn*64 + 8);
        uint4 nk;
        if (tid < 256) nk = *(const uint4*)(Kg + scn*512);

        const short* bk = ldsK[sc & 1][qtr];
        const short* bv = ldsV[sc & 1][qtr];
        #pragma unroll
        for (int h = 0; h < 2; ++h) {
            bf16x8 kf0 = *(const bf16x8*)(bk + (h*32 + c15)*8);
            bf16x8 kf1 = *(const bf16x8*)(bk + (h*32 + 16 + c15)*8);
            int col8 = ((h*4 + quad) ^ sw)*8;
            bf16x8 a0 = *(const bf16x8*)(bv + c15*64 + col8);
            bf16x8 a1 = *(const bf16x8*)(bv + (16 + c15)*64 + col8);
            f32x4 s0A = __builtin_amdgcn_mfma_f32_16x16x32_bf16(kf0, bq0, zero4, 0, 0, 0);
            f32x4 s1A = __builtin_amdgcn_mfma_f32_16x16x32_bf16(kf1, bq0, zero4, 0, 0, 0);
            f32x4 s0B = __builtin_amdgcn_mfma_f32_16x16x32_bf16(kf0, bq1, zero4, 0, 0, 0);
            f32x4 s1B = __builtin_amdgcn_mfma_f32_16x16x32_bf16(kf1, bq1, zero4, 0, 0, 0);
            U8 bpA, bpB;
            bpA.u[0] = packperm(__builtin_amdgcn_exp2f(s0A[0]), __builtin_amdgcn_exp2f(s0A[1]));
            bpA.u[1] = packperm(__builtin_amdgcn_exp2f(s0A[2]), __builtin_amdgcn_exp2f(s0A[3]));
            bpA.u[2] = packperm(__builtin_amdgcn_exp2f(s1A[0]), __builtin_amdgcn_exp2f(s1A[1]));
            bpA.u[3] = packperm(__builtin_amdgcn_exp2f(s1A[2]), __builtin_amdgcn_exp2f(s1A[3]));
            bpB.u[0] = packperm(__builtin_amdgcn_exp2f(s0B[0]), __builtin_amdgcn_exp2f(s0B[1]));
            bpB.u[1] = packperm(__builtin_amdgcn_exp2f(s0B[2]), __builtin_amdgcn_exp2f(s0B[3]));
            bpB.u[2] = packperm(__builtin_amdgcn_exp2f(s1B[0]), __builtin_amdgcn_exp2f(s1B[1]));
            bpB.u[3] = packperm(__builtin_amdgcn_exp2f(s1B[2]), __builtin_amdgcn_exp2f(s1B[3]));
            D0A = __builtin_amdgcn_mfma_f32_16x16x32_bf16(a0, bpA.v, D0A, 0, 0, 0);
            D1A = __builtin_amdgcn_mfma_f32_16x16x32_bf16(a1, bpA.v, D1A, 0, 0, 0);
            DlA = __builtin_amdgcn_mfma_f32_16x16x32_bf16(ones.v, bpA.v, DlA, 0, 0, 0);
            D0B = __builtin_amdgcn_mfma_f32_16x16x32_bf16(a0, bpB.v, D0B, 0, 0, 0);
            D1B = __builtin_amdgcn_mfma_f32_16x16x32_bf16(a1, bpB.v, D1B, 0, 0, 0);
            DlB = __builtin_amdgcn_mfma_f32_16x16x32_bf16(ones.v, bpB.v, DlB, 0, 0, 0);
        }
        int nb = (sc + 1) & 1;
        *(uint4*)&ldsV[nb][sqtr][vofs]     = nv0;
        *(uint4*)&ldsV[nb][sqtr][vofs + 8] = nv1;
        if (tid < 256) *(uint4*)&ldsK[nb][kqtr][kofs] = nk;
        __syncthreads();
    }

    // combine 4 quarter partials (stride-9: conflict-free)
    #pragma unroll
    for (int r = 1; r < 4; ++r) {
        if (qtr == r) {
            float* cA = &comb[qpair][0][lane*9];
            cA[0]=D0A[0]; cA[1]=D0A[1]; cA[2]=D0A[2]; cA[3]=D0A[3];
            cA[4]=D1A[0]; cA[5]=D1A[1]; cA[6]=D1A[2]; cA[7]=D1A[3];
            cA[8]=DlA[0];
            float* cB = &comb[qpair][1][lane*9];
            cB[0]=D0B[0]; cB[1]=D0B[1]; cB[2]=D0B[2]; cB[3]=D0B[3];
            cB[4]=D1B[0]; cB[5]=D1B[1]; cB[6]=D1B[2]; cB[7]=D1B[3];
            cB[8]=DlB[0];
        }
        __syncthreads();
        if (qtr == 0) {
            const float* cA = &comb[qpair][0][lane*9];
            D0A[0]+=cA[0]; D0A[1]+=cA[1]; D0A[2]+=cA[2]; D0A[3]+=cA[3];
            D1A[0]+=cA[4]; D1A[1]+=cA[5]; D1A[2]+=cA[6]; D1A[3]+=cA[7];
            DlA[0]+=cA[8];
            const float* cB = &comb[qpair][1][lane*9];
            D0B[0]+=cB[0]; D0B[1]+=cB[1]; D0B[2]+=cB[2]; D0B[3]+=cB[3];
            D1B[0]+=cB[4]; D1B[1]+=cB[5]; D1B[2]+=cB[6]; D1B[3]+=cB[7];
            DlB[0]+=cB[8];
        }
        __syncthreads();
    }
    if (qtr != 0) return;       // no barriers past this point

    float rlA = 1.0f / DlA[0];
    float rlB = 1.0f / DlB[0];
    U8 ByA, ByB;
    ByA.u[0] = pack2bf(D0A[0]*rlA, D0A[1]*rlA); ByA.u[1] = pack2bf(D0A[2]*rlA, D0A[3]*rlA);
    ByA.u[2] = pack2bf(D1A[0]*rlA, D1A[1]*rlA); ByA.u[3] = pack2bf(D1A[2]*rlA, D1A[3]*rlA);
    ByB.u[0] = pack2bf(D0B[0]*rlB, D0B[1]*rlB); ByB.u[1] = pack2bf(D0B[2]*rlB, D0B[3]*rlB);
    ByB.u[2] = pack2bf(D1B[0]*rlB, D1B[1]*rlB); ByB.u[3] = pack2bf(D1B[2]*rlB, D1B[3]*rlB);

    float gam = gamma[0];
    #pragma unroll
    for (int t = 0; t < 4; ++t) {
        int co = t*16 + c15;
        float4 wlo = *(const float4*)(wo + co*32 + quad*4);
        float4 whi = *(const float4*)(wo + co*32 + 16 + quad*4);
        U8 aw;
        aw.u[0] = pack2bf(wlo.x, wlo.y); aw.u[1] = pack2bf(wlo.z, wlo.w);
        aw.u[2] = pack2bf(whi.x, whi.y); aw.u[3] = pack2bf(whi.z, whi.w);
        f32x4 oA = __builtin_amdgcn_mfma_f32_16x16x32_bf16(aw.v, ByA.v, zero4, 0, 0, 0);
        f32x4 oB = __builtin_amdgcn_mfma_f32_16x16x32_bf16(aw.v, ByB.v, zero4, 0, 0, 0);
        #pragma unroll
        for (int r2 = 0; r2 < 4; ++r2) {
            int co_r = t*16 + quad*4 + r2;
            int base = ((b*CC + co_r) << 14) + q0 + c15;
            out[base]      = x[base]      + gam*oA[r2];
            out[base + 16] = x[base + 16] + gam*oB[r2];
        }
    }
}

// ---------------------------------------------------------------------------
// Workspace: Qb 512K @ 0, Kb 128K @ 524288, Vt 512K @ 655360.
// R8: proj launched twice (idempotent) — dur_total minus R7's 104.97us
// gives dur(proj) exactly. See proj_kernel comment.
// ---------------------------------------------------------------------------
extern "C" void kernel_launch(void* const* d_in, const int* in_sizes, int n_in,
                              void* d_out, int out_size, void* d_ws, size_t ws_size,
                              hipStream_t stream) {
    const float* x     = (const float*)d_in[0];
    const float* wt    = (const float*)d_in[1];
    const float* wp    = (const float*)d_in[2];
    const float* wg    = (const float*)d_in[3];
    const float* wo    = (const float*)d_in[4];
    const float* gamma = (const float*)d_in[5];
    float* out = (float*)d_out;

    char* ws = (char*)d_ws;
    short* Qb = (short*)(ws);
    short* Kb = (short*)(ws + 524288);
    short* Vt = (short*)(ws + 655360);

    dim3 g1(256, BB, 2);
    proj_kernel<<<g1, 256, 0, stream>>>(x, wt, wp, wg, Qb, Kb, Vt);
    proj_kernel<<<g1, 256, 0, stream>>>(x, wt, wp, wg, Qb, Kb, Vt);   // diagnostic duplicate
    attn_kernel<<<BB*NN/64, 512, 0, stream>>>(Qb, Kb, Vt, x, wo, gamma, out);
}